// Round 1
// baseline (110.243 us; speedup 1.0000x reference)
//
#include <hip/hip_runtime.h>

// SpikingLayer: node_x = W @ is_firing; v_acc = v + node_x; fire = v_acc > 1;
// outputs (concat): [x (copy), fire?1:0, fire?0:v_acc, node_x], each length N.
// Memory-bound on the 604 MB streaming read of W.

#define SPK_N      12288
#define SPK_NV4    (SPK_N / 4)      // 3072 float4 per row
#define SPK_BLOCK  256
#define SPK_WAVES  4                // waves per block
#define SPK_GRID   768              // 3072 waves total -> 4 rows per wave

__global__ __launch_bounds__(SPK_BLOCK, 1)
void spiking_layer_kernel(const float* __restrict__ x,
                          const float* __restrict__ W,
                          const float* __restrict__ f,
                          const float* __restrict__ v,
                          float* __restrict__ out)
{
    __shared__ float4 sf[SPK_NV4];  // 48 KB: is_firing staged once per block

    const int tid = threadIdx.x;

    // Stage is_firing into LDS (coalesced float4, 12 per thread).
    const float4* f4 = reinterpret_cast<const float4*>(f);
    #pragma unroll
    for (int k = 0; k < SPK_NV4 / SPK_BLOCK; ++k)
        sf[k * SPK_BLOCK + tid] = f4[k * SPK_BLOCK + tid];
    __syncthreads();

    const int wave  = tid >> 6;
    const int lane  = tid & 63;
    const int gwaves = SPK_GRID * SPK_WAVES;   // 3072

    for (int row = blockIdx.x * SPK_WAVES + wave; row < SPK_N; row += gwaves) {
        const float4* wrow =
            reinterpret_cast<const float4*>(W + (size_t)row * SPK_N);

        float acc = 0.0f;
        // 3072 float4 per row / 64 lanes = 48 float4 per lane, coalesced.
        #pragma unroll 8
        for (int k = 0; k < SPK_NV4 / 64; ++k) {
            const float4 wv = wrow[k * 64 + lane];
            const float4 fv = sf[k * 64 + lane];
            acc += wv.x * fv.x + wv.y * fv.y + wv.z * fv.z + wv.w * fv.w;
        }

        // Wave-level reduction (64 lanes).
        #pragma unroll
        for (int off = 32; off > 0; off >>= 1)
            acc += __shfl_down(acc, off, 64);

        if (lane == 0) {
            const float node_x = acc;
            const float v_acc  = v[row] + node_x;
            const bool  fire   = v_acc > 1.0f;
            out[row]               = x[row];                  // x passthrough
            out[SPK_N + row]       = fire ? 1.0f : 0.0f;      // is_firing_new
            out[2 * SPK_N + row]   = fire ? 0.0f : v_acc;     // v_new
            out[3 * SPK_N + row]   = node_x;                  // node_x
        }
    }
}

extern "C" void kernel_launch(void* const* d_in, const int* in_sizes, int n_in,
                              void* d_out, int out_size, void* d_ws, size_t ws_size,
                              hipStream_t stream)
{
    const float* x = (const float*)d_in[0];
    const float* W = (const float*)d_in[1];
    const float* f = (const float*)d_in[2];
    const float* v = (const float*)d_in[3];
    float* out = (float*)d_out;

    spiking_layer_kernel<<<SPK_GRID, SPK_BLOCK, 0, stream>>>(x, W, f, v, out);
}

// Round 3
// 95.145 us; speedup vs baseline: 1.1587x; 1.1587x over previous
//
#include <hip/hip_runtime.h>

// SpikingLayer: node_x = W @ is_firing; v_acc = v + node_x; fire = v_acc > 1;
// outputs (concat): [x (copy), fire?1:0, fire?0:v_acc, node_x], each length N.
// Memory-bound on the 604 MB streaming read of W (f32, N=12288).
//
// R1/R2: bf16 LDS staging of is_firing (24 KB -> 6 blocks/CU capacity),
//     2 rows per wave interleaved (2x MLP, overlapped reduce chains),
//     non-temporal W loads via native ext_vector_type (HIP float4 is a
//     struct and __builtin_nontemporal_load rejects it).

#define SPK_N      12288
#define SPK_BLOCK  256
#define SPK_GRID   1536             // 8 rows per block (4 waves x 2 rows)

typedef float  fx4 __attribute__((ext_vector_type(4)));

__global__ __launch_bounds__(SPK_BLOCK, 5)
void spiking_layer_kernel(const float* __restrict__ x,
                          const float* __restrict__ W,
                          const float* __restrict__ f,
                          const float* __restrict__ v,
                          float* __restrict__ out)
{
    __shared__ ushort sf[SPK_N];    // 24 KB: is_firing as bf16 (exact for 0/1)

    const int tid = threadIdx.x;

    // Stage is_firing -> LDS as bf16. 12 fx4 per thread, coalesced.
    const fx4* f4  = reinterpret_cast<const fx4*>(f);
    ushort4*   sf4 = reinterpret_cast<ushort4*>(sf);
    #pragma unroll
    for (int k = 0; k < SPK_N / 4 / SPK_BLOCK; ++k) {
        const fx4 fv = f4[k * SPK_BLOCK + tid];
        ushort4 u;
        u.x = (ushort)(__float_as_uint(fv.x) >> 16);
        u.y = (ushort)(__float_as_uint(fv.y) >> 16);
        u.z = (ushort)(__float_as_uint(fv.z) >> 16);
        u.w = (ushort)(__float_as_uint(fv.w) >> 16);
        sf4[k * SPK_BLOCK + tid] = u;
    }
    __syncthreads();

    const int wave = tid >> 6;
    const int lane = tid & 63;

    // Two consecutive rows per wave, fully interleaved.
    const int r0 = blockIdx.x * 8 + wave * 2;
    const int r1 = r0 + 1;

    const fx4* w0 = reinterpret_cast<const fx4*>(W + (size_t)r0 * SPK_N);
    const fx4* w1 = reinterpret_cast<const fx4*>(W + (size_t)r1 * SPK_N);
    const ushort4* sfv = reinterpret_cast<const ushort4*>(sf);

    float a0 = 0.0f, a1 = 0.0f;
    // 3072 fx4 per row / 64 lanes = 48 iterations.
    #pragma unroll 4
    for (int k = 0; k < SPK_N / 4 / 64; ++k) {
        const int idx = k * 64 + lane;
        const fx4 wv0 = __builtin_nontemporal_load(&w0[idx]);
        const fx4 wv1 = __builtin_nontemporal_load(&w1[idx]);
        const ushort4 u = sfv[idx];
        const float fx = __uint_as_float((unsigned)u.x << 16);
        const float fy = __uint_as_float((unsigned)u.y << 16);
        const float fz = __uint_as_float((unsigned)u.z << 16);
        const float fw = __uint_as_float((unsigned)u.w << 16);
        a0 += wv0.x * fx + wv0.y * fy + wv0.z * fz + wv0.w * fw;
        a1 += wv1.x * fx + wv1.y * fy + wv1.z * fz + wv1.w * fw;
    }

    // Wave reduction, both rows' chains interleaved (latency overlap).
    #pragma unroll
    for (int off = 32; off > 0; off >>= 1) {
        a0 += __shfl_down(a0, off, 64);
        a1 += __shfl_down(a1, off, 64);
    }

    if (lane == 0) {
        const float va0 = v[r0] + a0;
        const float va1 = v[r1] + a1;
        const bool  f0  = va0 > 1.0f;
        const bool  f1  = va1 > 1.0f;
        out[r0]              = x[r0];
        out[r1]              = x[r1];
        out[SPK_N + r0]      = f0 ? 1.0f : 0.0f;
        out[SPK_N + r1]      = f1 ? 1.0f : 0.0f;
        out[2 * SPK_N + r0]  = f0 ? 0.0f : va0;
        out[2 * SPK_N + r1]  = f1 ? 0.0f : va1;
        out[3 * SPK_N + r0]  = a0;
        out[3 * SPK_N + r1]  = a1;
    }
}

extern "C" void kernel_launch(void* const* d_in, const int* in_sizes, int n_in,
                              void* d_out, int out_size, void* d_ws, size_t ws_size,
                              hipStream_t stream)
{
    const float* x = (const float*)d_in[0];
    const float* W = (const float*)d_in[1];
    const float* f = (const float*)d_in[2];
    const float* v = (const float*)d_in[3];
    float* out = (float*)d_out;

    spiking_layer_kernel<<<SPK_GRID, SPK_BLOCK, 0, stream>>>(x, W, f, v, out);
}